// Round 12
// baseline (149.848 us; speedup 1.0000x reference)
//
#include <hip/hip_runtime.h>

#define N_TRACES 128
#define TLEN 32
#define IN_DIM 64
#define HID 128
#define G4 (4 * HID)            // 512 gate rows
#define BATCH (N_TRACES * TLEN) // 4096

typedef float f32x2 __attribute__((ext_vector_type(2)));
typedef float f32x4 __attribute__((ext_vector_type(4)));
typedef __bf16 bf16x8 __attribute__((ext_vector_type(8)));

// ---------- device helpers ----------

__device__ __forceinline__ float fast_sigmoid(float x) {
    return 1.0f / (1.0f + __expf(-x));
}
// tanh(x) = 1 - 2/(e^{2x}+1): stable at both extremes
__device__ __forceinline__ float fast_tanh(float x) {
    return 1.0f - 2.0f / (__expf(2.0f * x) + 1.0f);
}
// sum across the 4 lanes of a quad, result in all 4 lanes
__device__ __forceinline__ float quad_reduce(float x) {
    x += __int_as_float(__builtin_amdgcn_update_dpp(
        0, __float_as_int(x), 0xB1 /*quad_perm [1,0,3,2]*/, 0xF, 0xF, true));
    x += __int_as_float(__builtin_amdgcn_update_dpp(
        0, __float_as_int(x), 0x4E /*quad_perm [2,3,0,1]*/, 0xF, 0xF, true));
    return x;
}

// load 4 gate rows {u+128i}, k-slice [32s,32s+32) of a [512][128] matrix,
// stored as f32x2 k-pairs (for v_pk_fma_f32). Same 128 regs; pairs fall
// straight out of the float4 loads. Pin forbids rematerialization.
__device__ __forceinline__ void load_w2(const float* __restrict__ W, int u, int s,
                                        f32x2 (&w)[4][16]) {
    #pragma unroll
    for (int i = 0; i < 4; ++i) {
        const float* wr = W + (size_t)(u + 128 * i) * HID + 32 * s;
        #pragma unroll
        for (int j = 0; j < 8; ++j) {
            float4 v = *(const float4*)(wr + 4 * j);
            w[i][2 * j]     = (f32x2){v.x, v.y};
            w[i][2 * j + 1] = (f32x2){v.z, v.w};
        }
    }
    #pragma unroll
    for (int i = 0; i < 4; ++i)
        #pragma unroll
        for (int j = 0; j < 16; ++j)
            asm volatile("" : "+v"(w[i][j]));
}

// acc2[i] += k-paired dot: v_pk_fma_f32 does 2 k-elements per instruction
// (64 pk-FMA vs 128 scalar FMA). h pairs come free from the b128 reads.
__device__ __forceinline__ void matvec_pk(const f32x2 (&w)[4][16],
                                          const float* hb, f32x2 (&acc)[4]) {
    #pragma unroll
    for (int j = 0; j < 8; ++j) {
        float4 v = *(const float4*)(hb + 4 * j);
        const f32x2 h0 = (f32x2){v.x, v.y};
        const f32x2 h1 = (f32x2){v.z, v.w};
        #pragma unroll
        for (int i = 0; i < 4; ++i)
            acc[i] = __builtin_elementwise_fma(w[i][2 * j], h0, acc[i]);
        #pragma unroll
        for (int i = 0; i < 4; ++i)
            acc[i] = __builtin_elementwise_fma(w[i][2 * j + 1], h1, acc[i]);
    }
}

// ---------- MFMA helpers (r9/r12/r14/r15 HW-verified fragment conventions) ----------

// hi/lo split of 8 consecutive f32 into one bf16x8 pair
__device__ __forceinline__ void split8(const float* p, bf16x8& h, bf16x8& l) {
    float4 v0 = *(const float4*)(p);
    float4 v1 = *(const float4*)(p + 4);
    float f0[4] = {v0.x, v0.y, v0.z, v0.w};
    float f1[4] = {v1.x, v1.y, v1.z, v1.w};
    #pragma unroll
    for (int e = 0; e < 4; ++e) {
        __bf16 t0 = (__bf16)f0[e];
        h[e] = t0; l[e] = (__bf16)(f0[e] - (float)t0);
        __bf16 t1 = (__bf16)f1[e];
        h[4 + e] = t1; l[4 + e] = (__bf16)(f1[e] - (float)t1);
    }
}

// ---------- single fused kernel (128 blocks x 512 threads) ----------
// r17 = r16 (149.5 µs: fused phase-A MFMA input projection + quad fp32
// recurrences + MFMA phase C) with ONE change: phases B/D matvec moved to
// v_pk_fma_f32 (f32x2 k-pairs, __builtin_elementwise_fma) — halves the
// recurrence FMA issue (128 -> 64 instr). Summation order: pairwise along k,
// then .x+.y, then quad_reduce. Everything else byte-identical to r16.

__global__ __launch_bounds__(512) void fused_trace(
    const float* __restrict__ input,  // [4096][64]
    const float* __restrict__ Wih0,   // [512][64]
    const float* __restrict__ bih0,   // [512]
    const float* __restrict__ bhh0,   // [512]
    const float* __restrict__ Whh0,   // [512][128]
    const float* __restrict__ Wih1,   // [512][128]
    const float* __restrict__ bih1,   // [512]
    const float* __restrict__ bhh1,   // [512]
    const float* __restrict__ Whh1,   // [512][128]
    const float* __restrict__ Wlin,   // [128]
    const float* __restrict__ blin,   // [1]
    float* __restrict__ y)            // [4096]
{
    const int trace = blockIdx.x;
    const int tid = threadIdx.x;
    const int u = tid >> 2;
    const int s = tid & 3;
    const int pu = u + 4 * (u >> 5); // padded word index for unit u

    __shared__ float hs[TLEN][140];     // h1 then h2, padded (p(127)=139)
    __shared__ float xp[TLEN * G4];     // 64 KB: xproj0, then overwritten w/ xproj1

    f32x2 w[4][16];

    // ===== Phase A (MFMA): xp[t] = input_row(t) @ W_ih0^T + b_ih0 + b_hh0 =====
    // [32 t-rows x 64] @ [512 x 64]^T per block; K=64 -> kc<2. (r16, verified)
    {
        const int w8 = tid >> 6;       // wave 0..7
        const int lane = tid & 63;
        const int cl = lane & 15;
        const int q = lane >> 4;
        const int um = 16 * w8 + cl;   // this lane's B-row (gate unit)

        bf16x8 Bh[4][2], Bl[4][2];
        #pragma unroll
        for (int gi = 0; gi < 4; ++gi)
            #pragma unroll
            for (int kc = 0; kc < 2; ++kc)
                split8(Wih0 + (size_t)(um + 128 * gi) * IN_DIM + 32 * kc + 8 * q,
                       Bh[gi][kc], Bl[gi][kc]);
        float bb[4];
        #pragma unroll
        for (int gi = 0; gi < 4; ++gi)
            bb[gi] = bih0[um + 128 * gi] + bhh0[um + 128 * gi];

        #pragma unroll
        for (int mt = 0; mt < 2; ++mt) {
            bf16x8 ah[2], al[2];
            const float* pr = input + (size_t)(trace * TLEN + 16 * mt + cl) * IN_DIM;
            #pragma unroll
            for (int kc = 0; kc < 2; ++kc)
                split8(pr + 32 * kc + 8 * q, ah[kc], al[kc]);

            f32x4 acc[4];
            #pragma unroll
            for (int gi = 0; gi < 4; ++gi) acc[gi] = (f32x4){0.f, 0.f, 0.f, 0.f};
            #pragma unroll
            for (int gi = 0; gi < 4; ++gi) {
                #pragma unroll
                for (int kc = 0; kc < 2; ++kc) {
                    acc[gi] = __builtin_amdgcn_mfma_f32_16x16x32_bf16(ah[kc], Bh[gi][kc], acc[gi], 0, 0, 0);
                    acc[gi] = __builtin_amdgcn_mfma_f32_16x16x32_bf16(al[kc], Bh[gi][kc], acc[gi], 0, 0, 0);
                    acc[gi] = __builtin_amdgcn_mfma_f32_16x16x32_bf16(ah[kc], Bl[gi][kc], acc[gi], 0, 0, 0);
                }
            }
            #pragma unroll
            for (int gi = 0; gi < 4; ++gi)
                #pragma unroll
                for (int r = 0; r < 4; ++r)
                    xp[(16 * mt + 4 * q + r) * G4 + 128 * gi + um] = acc[gi][r] + bb[gi];
        }
    }
    load_w2(Whh0, u, s, w);
    __syncthreads();

    // ===== Phase B: layer-0 recurrence =====
    float xg[4], xgn[4];
    #pragma unroll
    for (int i = 0; i < 4; ++i) xg[i] = xp[128 * i + u];       // t=0 inputs
    #pragma unroll
    for (int i = 0; i < 4; ++i) xgn[i] = xp[G4 + 128 * i + u]; // t=1 inputs

    float c = 0.0f;
    // t=0 peel: no recurrent matvec (h(-1)=0)
    if (s == 0) {
        const float iv = fast_sigmoid(xg[0]);
        const float fv = fast_sigmoid(xg[1]);
        const float gv = fast_tanh(xg[2]);
        const float ov = fast_sigmoid(xg[3]);
        c = fv * c + iv * gv;
        hs[0][pu] = ov * fast_tanh(c);
    }
    __syncthreads();

    #pragma unroll 1
    for (int t = 1; t < TLEN; ++t) {
        #pragma unroll
        for (int i = 0; i < 4; ++i) xg[i] = xgn[i];

        f32x2 acc2[4];
        #pragma unroll
        for (int i = 0; i < 4; ++i) acc2[i] = (f32x2){0.f, 0.f};
        matvec_pk(w, &hs[t - 1][36 * s], acc2);
        float acc[4];
        #pragma unroll
        for (int i = 0; i < 4; ++i) acc[i] = quad_reduce(acc2[i].x + acc2[i].y);

        if (s == 0) {
            const float iv = fast_sigmoid(acc[0] + xg[0]);
            const float fv = fast_sigmoid(acc[1] + xg[1]);
            const float gv = fast_tanh(acc[2] + xg[2]);
            const float ov = fast_sigmoid(acc[3] + xg[3]);
            c = fv * c + iv * gv;
            hs[t][pu] = ov * fast_tanh(c);
        }
        // prefetch next step's gate inputs (xp read-only in this phase)
        if (t < TLEN - 1) {
            #pragma unroll
            for (int i = 0; i < 4; ++i)
                xgn[i] = xp[(t + 1) * G4 + 128 * i + u];
        }
        __syncthreads();
    }

    // ===== Phase C (MFMA): xp[t] = W_ih1 @ h1(t) + b_ih1 + b_hh1 =====
    // Batched over all 32 t-rows; no per-t barrier. (r15/r16, verified)
    {
        const int w8 = tid >> 6;       // wave 0..7
        const int lane = tid & 63;
        const int cl = lane & 15;
        const int q = lane >> 4;
        const int um = 16 * w8 + cl;   // this lane's B-row unit

        bf16x8 Bh[4][4], Bl[4][4];
        #pragma unroll
        for (int gi = 0; gi < 4; ++gi)
            #pragma unroll
            for (int kc = 0; kc < 4; ++kc)
                split8(Wih1 + (size_t)(um + 128 * gi) * HID + 32 * kc + 8 * q,
                       Bh[gi][kc], Bl[gi][kc]);
        float bim[4];
        #pragma unroll
        for (int gi = 0; gi < 4; ++gi)
            bim[gi] = bih1[um + 128 * gi] + bhh1[um + 128 * gi];

        #pragma unroll
        for (int mt = 0; mt < 2; ++mt) {
            // A-frags: h1 row t = 16*mt + cl; k = 32*kc + 8*q lives at
            // padded word 36*kc + 8*q — contiguous 8 floats per chunk.
            bf16x8 ah[4], al[4];
            #pragma unroll
            for (int kc = 0; kc < 4; ++kc)
                split8(&hs[16 * mt + cl][36 * kc + 8 * q], ah[kc], al[kc]);

            f32x4 acc[4];
            #pragma unroll
            for (int gi = 0; gi < 4; ++gi) acc[gi] = (f32x4){0.f, 0.f, 0.f, 0.f};
            #pragma unroll
            for (int gi = 0; gi < 4; ++gi) {
                #pragma unroll
                for (int kc = 0; kc < 4; ++kc) {
                    acc[gi] = __builtin_amdgcn_mfma_f32_16x16x32_bf16(ah[kc], Bh[gi][kc], acc[gi], 0, 0, 0);
                    acc[gi] = __builtin_amdgcn_mfma_f32_16x16x32_bf16(al[kc], Bh[gi][kc], acc[gi], 0, 0, 0);
                    acc[gi] = __builtin_amdgcn_mfma_f32_16x16x32_bf16(ah[kc], Bl[gi][kc], acc[gi], 0, 0, 0);
                }
            }
            #pragma unroll
            for (int gi = 0; gi < 4; ++gi)
                #pragma unroll
                for (int r = 0; r < 4; ++r)
                    xp[(16 * mt + 4 * q + r) * G4 + 128 * gi + um] = acc[gi][r] + bim[gi];
        }
    }
    __syncthreads();

    // ===== Phase D: layer-1 recurrence (h2 overwrites hs) =====
    load_w2(Whh1, u, s, w);
    #pragma unroll
    for (int i = 0; i < 4; ++i) xg[i] = xp[128 * i + u];       // t=0 inputs
    #pragma unroll
    for (int i = 0; i < 4; ++i) xgn[i] = xp[G4 + 128 * i + u]; // t=1 inputs

    c = 0.0f;
    // t=0 peel
    if (s == 0) {
        const float iv = fast_sigmoid(xg[0]);
        const float fv = fast_sigmoid(xg[1]);
        const float gv = fast_tanh(xg[2]);
        const float ov = fast_sigmoid(xg[3]);
        c = fv * c + iv * gv;
        hs[0][pu] = ov * fast_tanh(c);
    }
    __syncthreads();

    #pragma unroll 1
    for (int t = 1; t < TLEN; ++t) {
        #pragma unroll
        for (int i = 0; i < 4; ++i) xg[i] = xgn[i];

        f32x2 acc2[4];
        #pragma unroll
        for (int i = 0; i < 4; ++i) acc2[i] = (f32x2){0.f, 0.f};
        matvec_pk(w, &hs[t - 1][36 * s], acc2);
        float acc[4];
        #pragma unroll
        for (int i = 0; i < 4; ++i) acc[i] = quad_reduce(acc2[i].x + acc2[i].y);

        if (s == 0) {
            const float iv = fast_sigmoid(acc[0] + xg[0]);
            const float fv = fast_sigmoid(acc[1] + xg[1]);
            const float gv = fast_tanh(acc[2] + xg[2]);
            const float ov = fast_sigmoid(acc[3] + xg[3]);
            c = fv * c + iv * gv;
            hs[t][pu] = ov * fast_tanh(c);
        }
        if (t < TLEN - 1) {
            #pragma unroll
            for (int i = 0; i < 4; ++i)
                xgn[i] = xp[(t + 1) * G4 + 128 * i + u];
        }
        __syncthreads();
    }

    // ===== Phase E: y[trace*32+t] = dot(h2(t), W_lin) + b_lin =====
    if (tid < 128) {
        const int tq = tid >> 2;
        const int sq = tid & 3;
        float wl[32];
        #pragma unroll
        for (int j = 0; j < 8; ++j) {
            float4 v = *(const float4*)(Wlin + 32 * sq + 4 * j);
            wl[4 * j + 0] = v.x; wl[4 * j + 1] = v.y;
            wl[4 * j + 2] = v.z; wl[4 * j + 3] = v.w;
        }
        const float* hb = &hs[tq][36 * sq];
        float a = 0.f;
        #pragma unroll
        for (int j = 0; j < 8; ++j) {
            float4 v = *(const float4*)(hb + 4 * j);
            a = fmaf(v.x, wl[4 * j + 0], a);
            a = fmaf(v.y, wl[4 * j + 1], a);
            a = fmaf(v.z, wl[4 * j + 2], a);
            a = fmaf(v.w, wl[4 * j + 3], a);
        }
        a = quad_reduce(a);
        if (sq == 0) y[trace * TLEN + tq] = a + blin[0];
    }
}

// ---------- launch ----------

extern "C" void kernel_launch(void* const* d_in, const int* in_sizes, int n_in,
                              void* d_out, int out_size, void* d_ws, size_t ws_size,
                              hipStream_t stream) {
    const float* input = (const float*)d_in[0];  // [4096][64]
    const float* W_ih0 = (const float*)d_in[1];  // [512][64]
    const float* W_hh0 = (const float*)d_in[2];  // [512][128]
    const float* b_ih0 = (const float*)d_in[3];  // [512]
    const float* b_hh0 = (const float*)d_in[4];  // [512]
    const float* W_ih1 = (const float*)d_in[5];  // [512][128]
    const float* W_hh1 = (const float*)d_in[6];  // [512][128]
    const float* b_ih1 = (const float*)d_in[7];  // [512]
    const float* b_hh1 = (const float*)d_in[8];  // [512]
    const float* W_lin = (const float*)d_in[9];  // [1][128]
    const float* b_lin = (const float*)d_in[10]; // [1]
    float* out = (float*)d_out;                  // [4096]

    // ONE kernel: in-block MFMA input projection -> LSTM0 -> (MFMA) xproj1
    // -> LSTM1 -> linear readout. No workspace, no second dispatch.
    fused_trace<<<N_TRACES, 512, 0, stream>>>(input, W_ih0, b_ih0, b_hh0,
                                              W_hh0, W_ih1, b_ih1, b_hh1,
                                              W_hh1, W_lin, b_lin, out);
}

// Round 13
// 148.269 us; speedup vs baseline: 1.0106x; 1.0106x over previous
//
#include <hip/hip_runtime.h>

#define N_TRACES 128
#define TLEN 32
#define IN_DIM 64
#define HID 128
#define G4 (4 * HID)            // 512 gate rows
#define BATCH (N_TRACES * TLEN) // 4096

typedef float f32x4 __attribute__((ext_vector_type(4)));
typedef __bf16 bf16x8 __attribute__((ext_vector_type(8)));

// ---------- device helpers ----------

__device__ __forceinline__ float fast_sigmoid(float x) {
    return 1.0f / (1.0f + __expf(-x));
}
// tanh(x) = 1 - 2/(e^{2x}+1): stable at both extremes
__device__ __forceinline__ float fast_tanh(float x) {
    return 1.0f - 2.0f / (__expf(2.0f * x) + 1.0f);
}
// sum across the 4 lanes of a quad, result in all 4 lanes
__device__ __forceinline__ float quad_reduce(float x) {
    x += __int_as_float(__builtin_amdgcn_update_dpp(
        0, __float_as_int(x), 0xB1 /*quad_perm [1,0,3,2]*/, 0xF, 0xF, true));
    x += __int_as_float(__builtin_amdgcn_update_dpp(
        0, __float_as_int(x), 0x4E /*quad_perm [2,3,0,1]*/, 0xF, 0xF, true));
    return x;
}

// load 4 gate rows {u+128i}, k-slice [32s,32s+32) of a [512][128] matrix.
// Land in AGPRs (unified file); pin forbids rematerialization.
// NOTE (r17 post-mortem): scalar-FMA form retained deliberately — the pk-FMA
// variant (fewer instructions) was measured SLOWER: the recurrence step is
// latency-chain-bound, not issue-bound, and fewer instructions expose more of
// the fixed ~1700 cyc/step barrier+LDS+dependency floor.
__device__ __forceinline__ void load_w(const float* __restrict__ W, int u, int s,
                                       float (&w)[4][32]) {
    #pragma unroll
    for (int i = 0; i < 4; ++i) {
        const float* wr = W + (size_t)(u + 128 * i) * HID + 32 * s;
        #pragma unroll
        for (int j = 0; j < 8; ++j) {
            float4 v = *(const float4*)(wr + 4 * j);
            w[i][4 * j + 0] = v.x; w[i][4 * j + 1] = v.y;
            w[i][4 * j + 2] = v.z; w[i][4 * j + 3] = v.w;
        }
    }
    #pragma unroll
    for (int i = 0; i < 4; ++i)
        #pragma unroll
        for (int j = 0; j < 32; ++j)
            asm volatile("" : "+v"(w[i][j]));
}

// acc[i] += dot(w[i][:], hb[0:32]) ; hb must be 16B aligned
__device__ __forceinline__ void matvec_acc(const float (&w)[4][32],
                                           const float* hb, float (&acc)[4]) {
    #pragma unroll
    for (int j = 0; j < 8; ++j) {
        float4 v = *(const float4*)(hb + 4 * j);
        float hx[4] = {v.x, v.y, v.z, v.w};
        #pragma unroll
        for (int e = 0; e < 4; ++e) {
            #pragma unroll
            for (int i = 0; i < 4; ++i)
                acc[i] = fmaf(w[i][4 * j + e], hx[e], acc[i]);
        }
    }
}

// ---------- MFMA helpers (r9/r12/r14/r15 HW-verified fragment conventions) ----------

// hi/lo split of 8 consecutive f32 into one bf16x8 pair
__device__ __forceinline__ void split8(const float* p, bf16x8& h, bf16x8& l) {
    float4 v0 = *(const float4*)(p);
    float4 v1 = *(const float4*)(p + 4);
    float f0[4] = {v0.x, v0.y, v0.z, v0.w};
    float f1[4] = {v1.x, v1.y, v1.z, v1.w};
    #pragma unroll
    for (int e = 0; e < 4; ++e) {
        __bf16 t0 = (__bf16)f0[e];
        h[e] = t0; l[e] = (__bf16)(f0[e] - (float)t0);
        __bf16 t1 = (__bf16)f1[e];
        h[4 + e] = t1; l[4 + e] = (__bf16)(f1[e] - (float)t1);
    }
}

// ---------- single fused kernel (128 blocks x 512 threads) ----------
// r18 = exact revert to r16 (149.45 µs, the session best):
//   Phase A (MFMA): in-block input projection -> LDS xp  (no gemm dispatch,
//     no workspace, no HBM round-trip)
//   Phase B: layer-0 recurrence — fp32 quad structure (scalar FMA, DPP quad
//     reduce, xg register prefetch, t=0 peel)
//   Phase C (MFMA): xp[t] = W_ih1 @ h1(t), batched, barrier-free
//   Phase D: layer-1 recurrence (same structure as B)
//   Phase E: y readout (quad dot + reduce)
// Declared structural floor: 64 barrier-synced recurrence steps x ~2700 cyc
// latency chain (8 structural variants r5-r17 all converge here); kernel
// latency-bound (HBM 0.6%, VALU ~30%, MFMA ~1%).

__global__ __launch_bounds__(512) void fused_trace(
    const float* __restrict__ input,  // [4096][64]
    const float* __restrict__ Wih0,   // [512][64]
    const float* __restrict__ bih0,   // [512]
    const float* __restrict__ bhh0,   // [512]
    const float* __restrict__ Whh0,   // [512][128]
    const float* __restrict__ Wih1,   // [512][128]
    const float* __restrict__ bih1,   // [512]
    const float* __restrict__ bhh1,   // [512]
    const float* __restrict__ Whh1,   // [512][128]
    const float* __restrict__ Wlin,   // [128]
    const float* __restrict__ blin,   // [1]
    float* __restrict__ y)            // [4096]
{
    const int trace = blockIdx.x;
    const int tid = threadIdx.x;
    const int u = tid >> 2;
    const int s = tid & 3;
    const int pu = u + 4 * (u >> 5); // padded word index for unit u

    __shared__ float hs[TLEN][140];     // h1 then h2, padded (p(127)=139)
    __shared__ float xp[TLEN * G4];     // 64 KB: xproj0, then overwritten w/ xproj1

    float w[4][32];

    // ===== Phase A (MFMA): xp[t] = input_row(t) @ W_ih0^T + b_ih0 + b_hh0 =====
    // [32 t-rows x 64] @ [512 x 64]^T per block; K=64 -> kc<2.
    {
        const int w8 = tid >> 6;       // wave 0..7
        const int lane = tid & 63;
        const int cl = lane & 15;
        const int q = lane >> 4;
        const int um = 16 * w8 + cl;   // this lane's B-row (gate unit)

        bf16x8 Bh[4][2], Bl[4][2];
        #pragma unroll
        for (int gi = 0; gi < 4; ++gi)
            #pragma unroll
            for (int kc = 0; kc < 2; ++kc)
                split8(Wih0 + (size_t)(um + 128 * gi) * IN_DIM + 32 * kc + 8 * q,
                       Bh[gi][kc], Bl[gi][kc]);
        float bb[4];
        #pragma unroll
        for (int gi = 0; gi < 4; ++gi)
            bb[gi] = bih0[um + 128 * gi] + bhh0[um + 128 * gi];

        #pragma unroll
        for (int mt = 0; mt < 2; ++mt) {
            bf16x8 ah[2], al[2];
            const float* pr = input + (size_t)(trace * TLEN + 16 * mt + cl) * IN_DIM;
            #pragma unroll
            for (int kc = 0; kc < 2; ++kc)
                split8(pr + 32 * kc + 8 * q, ah[kc], al[kc]);

            f32x4 acc[4];
            #pragma unroll
            for (int gi = 0; gi < 4; ++gi) acc[gi] = (f32x4){0.f, 0.f, 0.f, 0.f};
            #pragma unroll
            for (int gi = 0; gi < 4; ++gi) {
                #pragma unroll
                for (int kc = 0; kc < 2; ++kc) {
                    acc[gi] = __builtin_amdgcn_mfma_f32_16x16x32_bf16(ah[kc], Bh[gi][kc], acc[gi], 0, 0, 0);
                    acc[gi] = __builtin_amdgcn_mfma_f32_16x16x32_bf16(al[kc], Bh[gi][kc], acc[gi], 0, 0, 0);
                    acc[gi] = __builtin_amdgcn_mfma_f32_16x16x32_bf16(ah[kc], Bl[gi][kc], acc[gi], 0, 0, 0);
                }
            }
            // write: xp[t][128*gi + um], t = 16*mt + 4*q + r
            #pragma unroll
            for (int gi = 0; gi < 4; ++gi)
                #pragma unroll
                for (int r = 0; r < 4; ++r)
                    xp[(16 * mt + 4 * q + r) * G4 + 128 * gi + um] = acc[gi][r] + bb[gi];
        }
    }
    load_w(Whh0, u, s, w);
    __syncthreads();

    // ===== Phase B: layer-0 recurrence =====
    float xg[4], xgn[4];
    #pragma unroll
    for (int i = 0; i < 4; ++i) xg[i] = xp[128 * i + u];       // t=0 inputs
    #pragma unroll
    for (int i = 0; i < 4; ++i) xgn[i] = xp[G4 + 128 * i + u]; // t=1 inputs

    float c = 0.0f;
    // t=0 peel: no recurrent matvec (h(-1)=0)
    if (s == 0) {
        const float iv = fast_sigmoid(xg[0]);
        const float fv = fast_sigmoid(xg[1]);
        const float gv = fast_tanh(xg[2]);
        const float ov = fast_sigmoid(xg[3]);
        c = fv * c + iv * gv;
        hs[0][pu] = ov * fast_tanh(c);
    }
    __syncthreads();

    #pragma unroll 1
    for (int t = 1; t < TLEN; ++t) {
        #pragma unroll
        for (int i = 0; i < 4; ++i) xg[i] = xgn[i];

        float acc[4] = {0.f, 0.f, 0.f, 0.f};
        matvec_acc(w, &hs[t - 1][36 * s], acc);
        #pragma unroll
        for (int i = 0; i < 4; ++i) acc[i] = quad_reduce(acc[i]);

        if (s == 0) {
            const float iv = fast_sigmoid(acc[0] + xg[0]);
            const float fv = fast_sigmoid(acc[1] + xg[1]);
            const float gv = fast_tanh(acc[2] + xg[2]);
            const float ov = fast_sigmoid(acc[3] + xg[3]);
            c = fv * c + iv * gv;
            hs[t][pu] = ov * fast_tanh(c);
        }
        // prefetch next step's gate inputs (xp read-only in this phase)
        if (t < TLEN - 1) {
            #pragma unroll
            for (int i = 0; i < 4; ++i)
                xgn[i] = xp[(t + 1) * G4 + 128 * i + u];
        }
        __syncthreads();
    }

    // ===== Phase C (MFMA): xp[t] = W_ih1 @ h1(t) + b_ih1 + b_hh1 =====
    // Batched over all 32 t-rows; no per-t barrier.
    {
        const int w8 = tid >> 6;       // wave 0..7
        const int lane = tid & 63;
        const int cl = lane & 15;
        const int q = lane >> 4;
        const int um = 16 * w8 + cl;   // this lane's B-row unit

        bf16x8 Bh[4][4], Bl[4][4];
        #pragma unroll
        for (int gi = 0; gi < 4; ++gi)
            #pragma unroll
            for (int kc = 0; kc < 4; ++kc)
                split8(Wih1 + (size_t)(um + 128 * gi) * HID + 32 * kc + 8 * q,
                       Bh[gi][kc], Bl[gi][kc]);
        float bim[4];
        #pragma unroll
        for (int gi = 0; gi < 4; ++gi)
            bim[gi] = bih1[um + 128 * gi] + bhh1[um + 128 * gi];

        #pragma unroll
        for (int mt = 0; mt < 2; ++mt) {
            // A-frags: h1 row t = 16*mt + cl; k = 32*kc + 8*q lives at
            // padded word 36*kc + 8*q — contiguous 8 floats per chunk.
            bf16x8 ah[4], al[4];
            #pragma unroll
            for (int kc = 0; kc < 4; ++kc)
                split8(&hs[16 * mt + cl][36 * kc + 8 * q], ah[kc], al[kc]);

            f32x4 acc[4];
            #pragma unroll
            for (int gi = 0; gi < 4; ++gi) acc[gi] = (f32x4){0.f, 0.f, 0.f, 0.f};
            #pragma unroll
            for (int gi = 0; gi < 4; ++gi) {
                #pragma unroll
                for (int kc = 0; kc < 4; ++kc) {
                    acc[gi] = __builtin_amdgcn_mfma_f32_16x16x32_bf16(ah[kc], Bh[gi][kc], acc[gi], 0, 0, 0);
                    acc[gi] = __builtin_amdgcn_mfma_f32_16x16x32_bf16(al[kc], Bh[gi][kc], acc[gi], 0, 0, 0);
                    acc[gi] = __builtin_amdgcn_mfma_f32_16x16x32_bf16(ah[kc], Bl[gi][kc], acc[gi], 0, 0, 0);
                }
            }
            #pragma unroll
            for (int gi = 0; gi < 4; ++gi)
                #pragma unroll
                for (int r = 0; r < 4; ++r)
                    xp[(16 * mt + 4 * q + r) * G4 + 128 * gi + um] = acc[gi][r] + bim[gi];
        }
    }
    __syncthreads();

    // ===== Phase D: layer-1 recurrence (h2 overwrites hs) =====
    load_w(Whh1, u, s, w);
    #pragma unroll
    for (int i = 0; i < 4; ++i) xg[i] = xp[128 * i + u];       // t=0 inputs
    #pragma unroll
    for (int i = 0; i < 4; ++i) xgn[i] = xp[G4 + 128 * i + u]; // t=1 inputs

    c = 0.0f;
    // t=0 peel
    if (s == 0) {
        const float iv = fast_sigmoid(xg[0]);
        const float fv = fast_sigmoid(xg[1]);
        const float gv = fast_tanh(xg[2]);
        const float ov = fast_sigmoid(xg[3]);
        c = fv * c + iv * gv;
        hs[0][pu] = ov * fast_tanh(c);
    }
    __syncthreads();

    #pragma unroll 1
    for (int t = 1; t < TLEN; ++t) {
        #pragma unroll
        for (int i = 0; i < 4; ++i) xg[i] = xgn[i];

        float acc[4] = {0.f, 0.f, 0.f, 0.f};
        matvec_acc(w, &hs[t - 1][36 * s], acc);
        #pragma unroll
        for (int i = 0; i < 4; ++i) acc[i] = quad_reduce(acc[i]);

        if (s == 0) {
            const float iv = fast_sigmoid(acc[0] + xg[0]);
            const float fv = fast_sigmoid(acc[1] + xg[1]);
            const float gv = fast_tanh(acc[2] + xg[2]);
            const float ov = fast_sigmoid(acc[3] + xg[3]);
            c = fv * c + iv * gv;
            hs[t][pu] = ov * fast_tanh(c);
        }
        if (t < TLEN - 1) {
            #pragma unroll
            for (int i = 0; i < 4; ++i)
                xgn[i] = xp[(t + 1) * G4 + 128 * i + u];
        }
        __syncthreads();
    }

    // ===== Phase E: y[trace*32+t] = dot(h2(t), W_lin) + b_lin =====
    if (tid < 128) {
        const int tq = tid >> 2;
        const int sq = tid & 3;
        float wl[32];
        #pragma unroll
        for (int j = 0; j < 8; ++j) {
            float4 v = *(const float4*)(Wlin + 32 * sq + 4 * j);
            wl[4 * j + 0] = v.x; wl[4 * j + 1] = v.y;
            wl[4 * j + 2] = v.z; wl[4 * j + 3] = v.w;
        }
        const float* hb = &hs[tq][36 * sq];
        float a = 0.f;
        #pragma unroll
        for (int j = 0; j < 8; ++j) {
            float4 v = *(const float4*)(hb + 4 * j);
            a = fmaf(v.x, wl[4 * j + 0], a);
            a = fmaf(v.y, wl[4 * j + 1], a);
            a = fmaf(v.z, wl[4 * j + 2], a);
            a = fmaf(v.w, wl[4 * j + 3], a);
        }
        a = quad_reduce(a);
        if (sq == 0) y[trace * TLEN + tq] = a + blin[0];
    }
}

// ---------- launch ----------

extern "C" void kernel_launch(void* const* d_in, const int* in_sizes, int n_in,
                              void* d_out, int out_size, void* d_ws, size_t ws_size,
                              hipStream_t stream) {
    const float* input = (const float*)d_in[0];  // [4096][64]
    const float* W_ih0 = (const float*)d_in[1];  // [512][64]
    const float* W_hh0 = (const float*)d_in[2];  // [512][128]
    const float* b_ih0 = (const float*)d_in[3];  // [512]
    const float* b_hh0 = (const float*)d_in[4];  // [512]
    const float* W_ih1 = (const float*)d_in[5];  // [512][128]
    const float* W_hh1 = (const float*)d_in[6];  // [512][128]
    const float* b_ih1 = (const float*)d_in[7];  // [512]
    const float* b_hh1 = (const float*)d_in[8];  // [512]
    const float* W_lin = (const float*)d_in[9];  // [1][128]
    const float* b_lin = (const float*)d_in[10]; // [1]
    float* out = (float*)d_out;                  // [4096]

    // ONE kernel: in-block MFMA input projection -> LSTM0 -> (MFMA) xproj1
    // -> LSTM1 -> linear readout. No workspace, no second dispatch.
    fused_trace<<<N_TRACES, 512, 0, stream>>>(input, W_ih0, b_ih0, b_hh0,
                                              W_hh0, W_ih1, b_ih1, b_hh1,
                                              W_hh1, W_lin, b_lin, out);
}